// Round 1
// baseline (379.541 us; speedup 1.0000x reference)
//
#include <hip/hip_runtime.h>
#include <cstdint>

#define PN 196   // 14*14 patches
#define PC 768   // channels
#define KC 16    // channel rows staged per chunk

// Stage 1: per-batch block. Computes channel-L2 norms, the 5-point sparse
// Gram entries, builds the sparse Laplacian row (5 coeffs per node), runs the
// factored Newton-Schulz X4 = X0 (I+R0)(I+R0^2)(I+R0^4)(I+R0^8) applied to
// attn*5 as 31 stencil matvecs in LDS, and writes F_map.
__global__ __launch_bounds__(256) void adb_stage1(
    const float* __restrict__ S, const float* __restrict__ attn,
    const float* __restrict__ lmbd, const float* __restrict__ beta,
    float* __restrict__ Fmap)
{
    const int b   = blockIdx.x;
    const int tid = threadIdx.x;

    __shared__ float rows[KC * PN];     // staged channel rows
    __shared__ float rnorm[PN];         // 1/||S[:,n]||
    __shared__ float va[PN], vv[PN], vu[PN], vt[PN], vs[PN];

    const float* Sb = S + (size_t)b * PC * PN;

    const bool lane = tid < PN;
    const int n = lane ? tid : 0;
    const int i = n / 14, j = n % 14;
    const bool has_l = lane && (j > 0);
    const bool has_r = lane && (j < 13);
    const bool has_u = lane && (i > 0);
    const bool has_d = lane && (i < 13);
    // clamped neighbor indices (garbage accumulators masked later by L=0)
    const int il = n - (has_l ? 1  : 0);
    const int ir = n + (has_r ? 1  : 0);
    const int iu = n - (has_u ? 14 : 0);
    const int id = n + (has_d ? 14 : 0);

    float acc_s = 0.f, acc_l = 0.f, acc_r = 0.f, acc_u = 0.f, acc_d = 0.f;

    for (int c0 = 0; c0 < PC; c0 += KC) {
        __syncthreads();
        const float4* src = (const float4*)(Sb + c0 * PN);
        float4* dst = (float4*)rows;
        #pragma unroll
        for (int k = 0; k < 4; k++) {            // 784 float4s, 256 threads
            int idx = tid + k * 256;
            if (idx < KC * PN / 4) dst[idx] = src[idx];
        }
        __syncthreads();
        if (lane) {
            #pragma unroll
            for (int cc = 0; cc < KC; cc++) {
                const float* r = rows + cc * PN;
                float s = r[n];
                acc_s += s * s;
                acc_l += s * r[il];
                acc_r += s * r[ir];
                acc_u += s * r[iu];
                acc_d += s * r[id];
            }
        }
    }

    const float lm = lmbd[0];
    const float bt = beta[0];

    __syncthreads();
    float rn = 0.f;
    if (lane) {
        rn = 1.0f / fmaxf(sqrtf(acc_s), 1e-12f);
        rnorm[n] = rn;
        va[n] = attn[(size_t)b * PN + n] * 5.0f;
    }
    __syncthreads();

    // Sparse Laplacian row: L[n,n] = deg*(lm*Enn-1)+1e-6 ; L[n,m] = 1-lm*Enm
    float Lc = 0.f, Ll = 0.f, Lr = 0.f, Lu = 0.f, Ld = 0.f;
    if (lane) {
        float deg = (float)((has_l?1:0) + (has_r?1:0) + (has_u?1:0) + (has_d?1:0));
        float Enn = (acc_s * rn * rn + 1.f) * 0.5f;
        Lc = deg * (lm * Enn - 1.f) + 1e-6f;
        if (has_l) Ll = 1.f - lm * ((acc_l * rn * rnorm[il] + 1.f) * 0.5f);
        if (has_r) Lr = 1.f - lm * ((acc_r * rn * rnorm[ir] + 1.f) * 0.5f);
        if (has_u) Lu = 1.f - lm * ((acc_u * rn * rnorm[iu] + 1.f) * 0.5f);
        if (has_d) Ld = 1.f - lm * ((acc_d * rn * rnorm[id] + 1.f) * 0.5f);
    }

    // y = L x (5-point stencil), block-wide
    auto matvec = [&](float* dstv, const float* srcv) {
        __syncthreads();
        float r = 0.f;
        if (lane) {
            r = Lc * srcv[n] + Ll * srcv[il] + Lr * srcv[ir]
              + Lu * srcv[iu] + Ld * srcv[id];
        }
        __syncthreads();
        if (lane) dstv[n] = r;
    };

    // v = X0 a = 0.01 * L a
    matvec(vt, va);
    if (lane) vv[n] = 0.01f * vt[n];

    // v <- (I + R0^(2^stage)) v,  R0 x = x - 0.01 L(Lx)
    #pragma unroll
    for (int stage = 0; stage < 4; stage++) {
        __syncthreads();
        if (lane) vu[n] = vv[n];
        const int k = 1 << stage;
        for (int it = 0; it < k; it++) {
            matvec(vt, vu);     // t = L u
            matvec(vs, vt);     // s = L t
            if (lane) vu[n] -= 0.01f * vs[n];   // u = u - 0.01 s = R0 u
        }
        __syncthreads();
        if (lane) vv[n] += vu[n];
    }

    __syncthreads();
    if (lane) {
        float Fd = vv[n];
        float Fdiff = bt * (Fd - tanhf(Fd / (bt + 1e-8f)));
        Fmap[(size_t)b * PN + n] = Fdiff;
    }
}

// Stage 2: S_new = S * (1 + F_map), float4 streaming
__global__ __launch_bounds__(256) void adb_stage2(
    const float* __restrict__ S, const float* __restrict__ Fmap,
    float* __restrict__ out, int total4)
{
    int idx = blockIdx.x * 256 + threadIdx.x;
    if (idx >= total4) return;
    float4 sv = ((const float4*)S)[idx];
    int e   = idx * 4;                 // element index (fits in int: 38.5M)
    int b   = e / (PC * PN);
    int rem = e - b * (PC * PN);
    int n0  = rem % PN;                // all 4 elems share b (150528 % 4 == 0)
    const float* Fb = Fmap + (size_t)b * PN;
    float f0 = Fb[n0];
    int n1 = (n0 + 1 == PN) ? 0 : n0 + 1; float f1 = Fb[n1];
    int n2 = (n1 + 1 == PN) ? 0 : n1 + 1; float f2 = Fb[n2];
    int n3 = (n2 + 1 == PN) ? 0 : n2 + 1; float f3 = Fb[n3];
    float4 o;
    o.x = sv.x * (1.f + f0);
    o.y = sv.y * (1.f + f1);
    o.z = sv.z * (1.f + f2);
    o.w = sv.w * (1.f + f3);
    ((float4*)out)[idx] = o;
}

extern "C" void kernel_launch(void* const* d_in, const int* in_sizes, int n_in,
                              void* d_out, int out_size, void* d_ws, size_t ws_size,
                              hipStream_t stream) {
    const float* S    = (const float*)d_in[0];
    const float* attn = (const float*)d_in[1];
    const float* lmbd = (const float*)d_in[2];
    const float* beta = (const float*)d_in[3];

    const int B = in_sizes[1] / PN;        // 256 (attn has B*196 elements)

    float* Snew = (float*)d_out;                       // [B,C,14,14]
    float* Fmap = (float*)d_out + (size_t)B * PC * PN; // [B,1,14,14]

    adb_stage1<<<B, 256, 0, stream>>>(S, attn, lmbd, beta, Fmap);

    int total4 = (B * PC * PN) / 4;
    adb_stage2<<<(total4 + 255) / 256, 256, 0, stream>>>(S, Fmap, Snew, total4);
}

// Round 2
// 310.927 us; speedup vs baseline: 1.2207x; 1.2207x over previous
//
#include <hip/hip_runtime.h>
#include <cstdint>

#define PN 196   // 14*14 patches
#define PC 768   // channels
#define KC 16    // channel rows staged per chunk

// ---------------------------------------------------------------------------
// Kernel 1: partial channel reduction. grid (NCH, B). Each block reduces
// PC/NCH channels of one batch into 5 partial dot-product rows:
//   acc_s[n] = sum_c S[c][n]^2, acc_{l,r,u,d}[n] = sum_c S[c][n]*S[c][n+-δ]
// ---------------------------------------------------------------------------
template<int NCH>
__global__ __launch_bounds__(256) void adb_reduce(
    const float* __restrict__ S, float* __restrict__ partials)
{
    constexpr int CPB = PC / NCH;
    const int b   = blockIdx.y;
    const int ch  = blockIdx.x;
    const int tid = threadIdx.x;

    __shared__ float rows[KC * PN];

    const float* Sb = S + (size_t)b * PC * PN + (size_t)ch * CPB * PN;

    const bool lane = tid < PN;
    const int n = lane ? tid : 0;
    const int i = n / 14, j = n % 14;
    const bool has_l = lane && (j > 0);
    const bool has_r = lane && (j < 13);
    const bool has_u = lane && (i > 0);
    const bool has_d = lane && (i < 13);
    const int il = n - (has_l ? 1  : 0);
    const int ir = n + (has_r ? 1  : 0);
    const int iu = n - (has_u ? 14 : 0);
    const int id = n + (has_d ? 14 : 0);

    float acc_s = 0.f, acc_l = 0.f, acc_r = 0.f, acc_u = 0.f, acc_d = 0.f;

    for (int c0 = 0; c0 < CPB; c0 += KC) {
        __syncthreads();
        const float4* src = (const float4*)(Sb + c0 * PN);
        float4* dst = (float4*)rows;
        #pragma unroll
        for (int k = 0; k < 4; k++) {            // 784 float4s, 256 threads
            int idx = tid + k * 256;
            if (idx < KC * PN / 4) dst[idx] = src[idx];
        }
        __syncthreads();
        if (lane) {
            #pragma unroll
            for (int cc = 0; cc < KC; cc++) {
                const float* r = rows + cc * PN;
                float s = r[n];
                acc_s += s * s;
                acc_l += s * r[il];
                acc_r += s * r[ir];
                acc_u += s * r[iu];
                acc_d += s * r[id];
            }
        }
    }

    if (lane) {
        float* P = partials + ((size_t)b * NCH + ch) * 5 * PN;
        P[0 * PN + n] = acc_s;
        P[1 * PN + n] = acc_l;
        P[2 * PN + n] = acc_r;
        P[3 * PN + n] = acc_u;
        P[4 * PN + n] = acc_d;
    }
}

// ---------------------------------------------------------------------------
// Kernel 2: per-batch solve. Sum partials, build the sparse Laplacian row
// (5 coeffs/node), run factored Newton-Schulz
//   X4 = X0 (I+R0)(I+R0^2)(I+R0^4)(I+R0^8),  R0 = I - 0.01 L^2
// applied to attn*5 as 31 stencil matvecs in LDS. Emit Fmap and G = 1+Fdiff.
// ---------------------------------------------------------------------------
template<int NCH>
__global__ __launch_bounds__(256) void adb_solve(
    const float* __restrict__ partials, const float* __restrict__ attn,
    const float* __restrict__ lmbd, const float* __restrict__ beta,
    float* __restrict__ Fmap, float* __restrict__ Gmap)
{
    const int b   = blockIdx.x;
    const int tid = threadIdx.x;

    __shared__ float rnorm[PN];
    __shared__ float va[PN], vv[PN], vu[PN], vt[PN], vs[PN];

    const bool lane = tid < PN;
    const int n = lane ? tid : 0;
    const int i = n / 14, j = n % 14;
    const bool has_l = lane && (j > 0);
    const bool has_r = lane && (j < 13);
    const bool has_u = lane && (i > 0);
    const bool has_d = lane && (i < 13);
    const int il = n - (has_l ? 1  : 0);
    const int ir = n + (has_r ? 1  : 0);
    const int iu = n - (has_u ? 14 : 0);
    const int id = n + (has_d ? 14 : 0);

    float acc_s = 0.f, acc_l = 0.f, acc_r = 0.f, acc_u = 0.f, acc_d = 0.f;
    if (lane) {
        const float* P = partials + (size_t)b * NCH * 5 * PN;
        #pragma unroll
        for (int ch = 0; ch < NCH; ch++) {
            const float* Pc = P + ch * 5 * PN;
            acc_s += Pc[0 * PN + n];
            acc_l += Pc[1 * PN + n];
            acc_r += Pc[2 * PN + n];
            acc_u += Pc[3 * PN + n];
            acc_d += Pc[4 * PN + n];
        }
    }

    const float lm = lmbd[0];
    const float bt = beta[0];

    float rn = 0.f;
    if (lane) {
        rn = 1.0f / fmaxf(sqrtf(acc_s), 1e-12f);
        rnorm[n] = rn;
        va[n] = attn[(size_t)b * PN + n] * 5.0f;
    }
    __syncthreads();

    float Lc = 0.f, Ll = 0.f, Lr = 0.f, Lu = 0.f, Ld = 0.f;
    if (lane) {
        float deg = (float)((has_l?1:0) + (has_r?1:0) + (has_u?1:0) + (has_d?1:0));
        float Enn = (acc_s * rn * rn + 1.f) * 0.5f;
        Lc = deg * (lm * Enn - 1.f) + 1e-6f;
        if (has_l) Ll = 1.f - lm * ((acc_l * rn * rnorm[il] + 1.f) * 0.5f);
        if (has_r) Lr = 1.f - lm * ((acc_r * rn * rnorm[ir] + 1.f) * 0.5f);
        if (has_u) Lu = 1.f - lm * ((acc_u * rn * rnorm[iu] + 1.f) * 0.5f);
        if (has_d) Ld = 1.f - lm * ((acc_d * rn * rnorm[id] + 1.f) * 0.5f);
    }

    auto matvec = [&](float* dstv, const float* srcv) {
        __syncthreads();
        float r = 0.f;
        if (lane) {
            r = Lc * srcv[n] + Ll * srcv[il] + Lr * srcv[ir]
              + Lu * srcv[iu] + Ld * srcv[id];
        }
        __syncthreads();
        if (lane) dstv[n] = r;
    };

    // v = X0 a = 0.01 * L a
    matvec(vt, va);
    if (lane) vv[n] = 0.01f * vt[n];

    // v <- (I + R0^(2^stage)) v
    #pragma unroll
    for (int stage = 0; stage < 4; stage++) {
        __syncthreads();
        if (lane) vu[n] = vv[n];
        const int k = 1 << stage;
        for (int it = 0; it < k; it++) {
            matvec(vt, vu);
            matvec(vs, vt);
            if (lane) vu[n] -= 0.01f * vs[n];
        }
        __syncthreads();
        if (lane) vv[n] += vu[n];
    }

    __syncthreads();
    if (lane) {
        float Fd = vv[n];
        float Fdiff = bt * (Fd - tanhf(Fd / (bt + 1e-8f)));
        Fmap[(size_t)b * PN + n] = Fdiff;
        Gmap[(size_t)b * PN + n] = 1.0f + Fdiff;
    }
}

// ---------------------------------------------------------------------------
// Kernel 3: S_new = S * G. grid (147, B): each block handles 1024 consecutive
// floats of one batch; G row (196 floats + 3 wrap) staged in LDS.
// ---------------------------------------------------------------------------
__global__ __launch_bounds__(256) void adb_scale(
    const float* __restrict__ S, const float* __restrict__ Gmap,
    float* __restrict__ out)
{
    const int b   = blockIdx.y;
    const int tid = threadIdx.x;

    __shared__ float Gs[PN + 3];
    const float* Gb = Gmap + (size_t)b * PN;
    if (tid < PN / 4) ((float4*)Gs)[tid] = ((const float4*)Gb)[tid];
    if (tid >= 64 && tid < 67) Gs[PN + (tid - 64)] = Gb[tid - 64];  // wrap
    __syncthreads();

    const int off = blockIdx.x * 1024 + tid * 4;   // < 150528
    const int n0  = off % PN;                      // magic-mul, constant PN
    const size_t base = (size_t)b * PC * PN + off;
    float4 sv = *(const float4*)(S + base);
    float4 o;
    o.x = sv.x * Gs[n0];
    o.y = sv.y * Gs[n0 + 1];
    o.z = sv.z * Gs[n0 + 2];
    o.w = sv.w * Gs[n0 + 3];
    *(float4*)(out + base) = o;
}

extern "C" void kernel_launch(void* const* d_in, const int* in_sizes, int n_in,
                              void* d_out, int out_size, void* d_ws, size_t ws_size,
                              hipStream_t stream) {
    const float* S    = (const float*)d_in[0];
    const float* attn = (const float*)d_in[1];
    const float* lmbd = (const float*)d_in[2];
    const float* beta = (const float*)d_in[3];

    const int B = in_sizes[1] / PN;                    // 256

    float* Snew = (float*)d_out;                       // [B,C,14,14]
    float* Fmap = (float*)d_out + (size_t)B * PC * PN; // [B,1,14,14]
    float* ws   = (float*)d_ws;

    const size_t need8 = ((size_t)B * 8 * 5 * PN + (size_t)B * PN) * sizeof(float);
    const size_t need2 = ((size_t)B * 2 * 5 * PN + (size_t)B * PN) * sizeof(float);
    const size_t need1 = ((size_t)B * 1 * 5 * PN + (size_t)B * PN) * sizeof(float);

    if (ws_size >= need8) {
        float* partials = ws;
        float* Gmap = ws + (size_t)B * 8 * 5 * PN;
        adb_reduce<8><<<dim3(8, B), 256, 0, stream>>>(S, partials);
        adb_solve<8><<<B, 256, 0, stream>>>(partials, attn, lmbd, beta, Fmap, Gmap);
        adb_scale<<<dim3((PC * PN) / 1024, B), 256, 0, stream>>>(S, Gmap, Snew);
    } else if (ws_size >= need2) {
        float* partials = ws;
        float* Gmap = ws + (size_t)B * 2 * 5 * PN;
        adb_reduce<2><<<dim3(2, B), 256, 0, stream>>>(S, partials);
        adb_solve<2><<<B, 256, 0, stream>>>(partials, attn, lmbd, beta, Fmap, Gmap);
        adb_scale<<<dim3((PC * PN) / 1024, B), 256, 0, stream>>>(S, Gmap, Snew);
    } else {
        // minimal-scratch fallback
        float* partials = ws;
        float* Gmap = ws + (size_t)B * 1 * 5 * PN;
        (void)need1;
        adb_reduce<1><<<dim3(1, B), 256, 0, stream>>>(S, partials);
        adb_solve<1><<<B, 256, 0, stream>>>(partials, attn, lmbd, beta, Fmap, Gmap);
        adb_scale<<<dim3((PC * PN) / 1024, B), 256, 0, stream>>>(S, Gmap, Snew);
    }
}